// Round 5
// baseline (109.532 us; speedup 1.0000x reference)
//
#include <hip/hip_runtime.h>

// SequentialSparsemax: (8, 16, 262144) f32.
// pass1: sparsemax over 16 instruments at every (b, t).
// pass2: sparsemax over each 64-sample frame per (b, inst).
//
// Zero-LDS design: one wave = one (16 inst x 64 time) frame; lane = time.
//   pass1: lane-serial sort16 over the 16 insts (each lane owns a column).
//   pass2: per inst, cross-lane ascending bitonic over 64 lanes
//          (ds_swizzle / ds_bpermute, compile-time keepmax masks), DPP
//          prefix-sum, support count via ballot+popcount (mirrors the
//          reference's sum(support)), tau broadcast via readlane.
// No __shared__, ~42 live VGPRs -> 8 waves/SIMD occupancy possible.

#define T_DIM   262144
#define N_INST  16
#define B_DIM   8
#define NFRAME  (T_DIM / 64)          // 4096 frames per batch
#define WPB     4                     // independent waves per block

// ---------- lane-serial bitonic (pass 1) ----------
template<int N, int K, int S>
__device__ __forceinline__ void bstage(float (&a)[N]) {
#pragma unroll
  for (int i = 0; i < N; ++i) {
    const int l = i ^ S;
    if (l > i) {
      const float x = a[i], y = a[l];
      const float hi = fmaxf(x, y), lo = fminf(x, y);
      const bool desc = ((i & K) == 0);
      a[i] = desc ? hi : lo;
      a[l] = desc ? lo : hi;
    }
  }
}

__device__ __forceinline__ void sort_desc16(float (&a)[16]) {
  bstage<16, 2, 1>(a);
  bstage<16, 4, 2>(a);  bstage<16, 4, 1>(a);
  bstage<16, 8, 4>(a);  bstage<16, 8, 2>(a);  bstage<16, 8, 1>(a);
  bstage<16, 16, 8>(a); bstage<16, 16, 4>(a); bstage<16, 16, 2>(a); bstage<16, 16, 1>(a);
}

// z sorted descending. tau = max_k (cs_k - 1)/k (exact max-identity).
__device__ __forceinline__ float tau16(const float (&z)[16]) {
  float d = z[0] - 1.0f;  // cs - 1
  float tau = d;          // k = 1
#pragma unroll
  for (int k = 1; k < 16; ++k) {
    d += z[k];
    tau = fmaxf(tau, d * (1.0f / (float)(k + 1)));
  }
  return tau;
}

// ---------- cross-lane helpers (pass 2) ----------
template<int S>
__device__ __forceinline__ float shfl_xor_f(float x, int idx32) {
  if constexpr (S == 32) {
    return __int_as_float(__builtin_amdgcn_ds_bpermute(idx32, __float_as_int(x)));
  } else {
    // BitMode swizzle: offset = (xor<<10) | (or<<5) | and(0x1f)
    return __int_as_float(
        __builtin_amdgcn_ds_swizzle(__float_as_int(x), (S << 10) | 0x1f));
  }
}

// One ascending-bitonic stage across lanes; keepmax = bitK(lane)^bitS(lane)
// (compile-time exprs of lane, CSE'd across the 16 unrolled insts).
template<int K, int S>
__device__ __forceinline__ void xstage(float& B, int lane, int idx32) {
  const float y = shfl_xor_f<S>(B, idx32);
  const bool keepmax = (((lane & K) != 0) ^ ((lane & S) != 0));
  B = keepmax ? fmaxf(B, y) : fminf(B, y);
}

__device__ __forceinline__ void xsort64_asc(float& B, int lane, int idx32) {
  xstage<2, 1>(B, lane, idx32);
  xstage<4, 2>(B, lane, idx32);   xstage<4, 1>(B, lane, idx32);
  xstage<8, 4>(B, lane, idx32);   xstage<8, 2>(B, lane, idx32);   xstage<8, 1>(B, lane, idx32);
  xstage<16, 8>(B, lane, idx32);  xstage<16, 4>(B, lane, idx32);  xstage<16, 2>(B, lane, idx32);  xstage<16, 1>(B, lane, idx32);
  xstage<32, 16>(B, lane, idx32); xstage<32, 8>(B, lane, idx32);  xstage<32, 4>(B, lane, idx32);  xstage<32, 2>(B, lane, idx32);  xstage<32, 1>(B, lane, idx32);
  xstage<64, 32>(B, lane, idx32); xstage<64, 16>(B, lane, idx32); xstage<64, 8>(B, lane, idx32);  xstage<64, 4>(B, lane, idx32);  xstage<64, 2>(B, lane, idx32);  xstage<64, 1>(B, lane, idx32);
}

// AMD-canonical wave64 inclusive prefix-sum via DPP (row_shr + bcast15/31).
__device__ __forceinline__ float iscan_add(float x) {
  int t;
  t = __builtin_amdgcn_update_dpp(0, __float_as_int(x), 0x111, 0xf, 0xf, false);
  x += __int_as_float(t);  // row_shr:1
  t = __builtin_amdgcn_update_dpp(0, __float_as_int(x), 0x112, 0xf, 0xf, false);
  x += __int_as_float(t);  // row_shr:2
  t = __builtin_amdgcn_update_dpp(0, __float_as_int(x), 0x114, 0xf, 0xf, false);
  x += __int_as_float(t);  // row_shr:4
  t = __builtin_amdgcn_update_dpp(0, __float_as_int(x), 0x118, 0xf, 0xf, false);
  x += __int_as_float(t);  // row_shr:8
  t = __builtin_amdgcn_update_dpp(0, __float_as_int(x), 0x142, 0xa, 0xf, false);
  x += __int_as_float(t);  // row_bcast:15 -> rows 1,3
  t = __builtin_amdgcn_update_dpp(0, __float_as_int(x), 0x143, 0xc, 0xf, false);
  x += __int_as_float(t);  // row_bcast:31 -> rows 2,3
  return x;
}

__device__ __forceinline__ float rcp_fast(float x) {
#if __has_builtin(__builtin_amdgcn_rcpf)
  return __builtin_amdgcn_rcpf(x);
#else
  return 1.0f / x;
#endif
}

__global__ __launch_bounds__(256, 8) void seq_sparsemax_kernel(
    const float* __restrict__ in, float* __restrict__ out) {
  const int lane = threadIdx.x & 63;
  const int wid  = blockIdx.x * WPB + (threadIdx.x >> 6);  // frame id, 0..32767
  const int b    = wid >> 12;            // / NFRAME
  const int fr   = wid & (NFRAME - 1);

  const int idx32   = ((lane ^ 32) << 2);     // bpermute index for S=32
  const float lane1f = (float)(lane + 1);

  // ---- load: A[i] = in[b, i, fr*64 + lane]; 64 lanes = coalesced 256B ----
  const size_t base = (size_t)b * N_INST * T_DIM + (size_t)fr * 64 + lane;
  float A[N_INST];
#pragma unroll
  for (int i = 0; i < N_INST; ++i) A[i] = in[base + (size_t)i * T_DIM];

  // ---- pass 1 (lane-serial): sparsemax over the 16 insts of this column ----
  {
    float z[N_INST];
#pragma unroll
    for (int i = 0; i < N_INST; ++i) z[i] = A[i];
    sort_desc16(z);
    const float tau1 = tau16(z);
    // Store NEGATED pass-1 result: Yn = -max(A - tau1, 0) = min(tau1 - A, 0).
#pragma unroll
    for (int i = 0; i < N_INST; ++i) A[i] = fminf(tau1 - A[i], 0.0f);
  }

  // ---- pass 2 (cross-lane): sparsemax over each inst's 64-sample frame ----
#pragma unroll
  for (int i = 0; i < N_INST; ++i) {
    float B = A[i];                 // negated values: ascending sort of B
    xsort64_asc(B, lane, idx32);    // lane L holds L-th largest original
    const float pref = iscan_add(B);      // prefix sum of negatives
    const float zk = -B;                  // k-th largest (desc), k = lane+1
    const float cs = -pref;               // cumsum of sorted-desc
    // support flag, exactly the reference's 1 + k*z_k > cs_k; k* = sum(flags)
    const bool sup = fmaf(zk, lane1f, 1.0f) > cs;
    const unsigned long long m = __ballot(sup);
    const int kstar = (int)__popcll(m);   // wave-uniform (whole wave = row)
    const float cs_at = -__int_as_float(
        __builtin_amdgcn_readlane(__float_as_int(pref), kstar - 1));
    const float kf = (float)kstar;
    const float tau = (cs_at - 1.0f) * rcp_fast(kf);
    // out = max(y - tau, 0) with y = -A[i]  =>  max(-(A[i] + tau), 0)
    const float res = fmaxf(-(A[i] + tau), 0.0f);
    out[base + (size_t)i * T_DIM] = res;
  }
}

extern "C" void kernel_launch(void* const* d_in, const int* in_sizes, int n_in,
                              void* d_out, int out_size, void* d_ws, size_t ws_size,
                              hipStream_t stream) {
  const float* in = (const float*)d_in[0];
  float* out = (float*)d_out;
  const int grid = B_DIM * NFRAME / WPB;  // 8192 blocks x 4 waves = 32768 waves
  seq_sparsemax_kernel<<<grid, 64 * WPB, 0, stream>>>(in, out);
}

// Round 6
// 51.975 us; speedup vs baseline: 2.1074x; 2.1074x over previous
//
#include <hip/hip_runtime.h>

// SequentialSparsemax: (8, 16, 262144) f32.
// pass1: sparsemax over 16 instruments at every (b, t).
// pass2: sparsemax over each 64-sample frame per (b, inst).
//
// Fused; one wave per (16 inst x 256 time) tile; 4 independent waves per
// 256-thread workgroup. Serial per-lane sorts (VALU-economical).
// LDS cut to 4 KiB/wave: transpose in 4 rounds of 4 insts; the 16 lanes
// whose pass-2 rows live in that round's insts gather then. Pass-1 results
// A[16][4] stay in registers for phase-3 (no LDS re-read).
// __launch_bounds__(256,3): 170-VGPR budget, no spills, ~12 waves/CU.

#define T_DIM   262144
#define N_INST  16
#define B_DIM   8
#define CHUNK   256                   // time samples per wave-tile (4 frames)
#define NCHUNK  (T_DIM / CHUNK)       // 1024
#define WPB     4                     // independent waves per block

// One bitonic stage; K,S compile-time so `desc` folds and all indices are
// constants after unroll (pure SSA renaming, ~2 VALU per compare-exchange).
template<int N, int K, int S>
__device__ __forceinline__ void bstage(float (&a)[N]) {
#pragma unroll
  for (int i = 0; i < N; ++i) {
    const int l = i ^ S;
    if (l > i) {
      const float x = a[i], y = a[l];
      const float hi = fmaxf(x, y), lo = fminf(x, y);
      const bool desc = ((i & K) == 0);
      a[i] = desc ? hi : lo;
      a[l] = desc ? lo : hi;
    }
  }
}

__device__ __forceinline__ void sort_desc16(float (&a)[16]) {
  bstage<16, 2, 1>(a);
  bstage<16, 4, 2>(a);  bstage<16, 4, 1>(a);
  bstage<16, 8, 4>(a);  bstage<16, 8, 2>(a);  bstage<16, 8, 1>(a);
  bstage<16, 16, 8>(a); bstage<16, 16, 4>(a); bstage<16, 16, 2>(a); bstage<16, 16, 1>(a);
}

__device__ __forceinline__ void sort_desc64(float (&a)[64]) {
  bstage<64, 2, 1>(a);
  bstage<64, 4, 2>(a);   bstage<64, 4, 1>(a);
  bstage<64, 8, 4>(a);   bstage<64, 8, 2>(a);   bstage<64, 8, 1>(a);
  bstage<64, 16, 8>(a);  bstage<64, 16, 4>(a);  bstage<64, 16, 2>(a);  bstage<64, 16, 1>(a);
  bstage<64, 32, 16>(a); bstage<64, 32, 8>(a);  bstage<64, 32, 4>(a);  bstage<64, 32, 2>(a);  bstage<64, 32, 1>(a);
  bstage<64, 64, 32>(a); bstage<64, 64, 16>(a); bstage<64, 64, 8>(a);  bstage<64, 64, 4>(a);  bstage<64, 64, 2>(a);  bstage<64, 64, 1>(a);
}

// z sorted descending. tau = max_k (cs_k - 1)/k (exact max-identity:
// h(k) rises exactly while the reference's support condition holds).
template<int N>
__device__ __forceinline__ float sparsemax_tau(const float (&z)[N]) {
  float cs = z[0];
  float tau = cs - 1.0f;  // k = 1
#pragma unroll
  for (int k = 1; k < N; ++k) {
    cs += z[k];
    tau = fmaxf(tau, (cs - 1.0f) * (1.0f / (float)(k + 1)));
  }
  return tau;
}

// lgkm-only fence: orders this wave's own-LDS ops without draining vmcnt.
// Waves within the block use disjoint LDS quarters => no s_barrier.
__device__ __forceinline__ void lds_fence() {
  asm volatile("s_waitcnt lgkmcnt(0)" ::: "memory");
  __builtin_amdgcn_sched_barrier(0);
}

__global__ __launch_bounds__(256, 3) void seq_sparsemax_kernel(
    const float* __restrict__ in, float* __restrict__ out) {
  __shared__ float lds[WPB * 4 * CHUNK];  // 4 waves x 4 KiB = 16 KiB

  const int lane = threadIdx.x & 63;
  const int wave = threadIdx.x >> 6;
  float* __restrict__ q = &lds[wave * 4 * CHUNK];

  const int tid   = blockIdx.x * WPB + wave;   // tile index 0..8191
  const int b     = tid >> 10;                 // / NCHUNK
  const int chunk = tid & (NCHUNK - 1);
  const size_t base = (size_t)b * N_INST * T_DIM + (size_t)chunk * CHUNK + 4 * lane;

  // ---- load: A[i][j] = in[b, i, t0 + 4*lane + j], coalesced float4 ----
  float A[N_INST][4];
#pragma unroll
  for (int i = 0; i < N_INST; ++i) {
    const float4 v = *reinterpret_cast<const float4*>(in + base + (size_t)i * T_DIM);
    A[i][0] = v.x; A[i][1] = v.y; A[i][2] = v.z; A[i][3] = v.w;
  }

  // ---- pass 1: sparsemax over instruments at each of this lane's 4 times ----
#pragma unroll
  for (int j = 0; j < 4; ++j) {
    float z[N_INST];
#pragma unroll
    for (int i = 0; i < N_INST; ++i) z[i] = A[i][j];
    sort_desc16(z);
    const float tau = sparsemax_tau(z);
#pragma unroll
    for (int i = 0; i < N_INST; ++i) A[i][j] = fmaxf(A[i][j] - tau, 0.0f);
  }

  // ---- 4-round transpose through 4 KiB LDS ----
  // Store swizzle for (slot s, time t): u = t ^ (s<<2) ^ (((t>>6)&3)<<4);
  // float index s*CHUNK + u. Keeps write & read patterns <=2-way (free).
  const int wt    = 4 * lane;           // this lane's time offset (write side)
  const int wf2   = lane >> 4;          // (wt>>6): frame of this lane's times
  const int i2    = lane >> 2;          // this lane's pass-2 row: inst
  const int f2    = lane & 3;           //                         frame
  const int glane = i2 >> 2;            // round in which this lane gathers
  const int s2    = i2 & 3;             // its slot within that round

  float w[64];
#pragma unroll
  for (int g = 0; g < 4; ++g) {
    if (g > 0) lds_fence();  // WAR: previous round's reads done
    // stage insts 4g..4g+3 into slots 0..3
#pragma unroll
    for (int s = 0; s < 4; ++s) {
      const int u = wt ^ (s << 2) ^ (wf2 << 4);
      *reinterpret_cast<float4*>(&q[s * CHUNK + u]) =
          make_float4(A[4 * g + s][0], A[4 * g + s][1],
                      A[4 * g + s][2], A[4 * g + s][3]);
    }
    lds_fence();  // RAW: writes visible
    if (glane == g) {
#pragma unroll
      for (int j = 0; j < 16; ++j) {
        const int t = f2 * 64 + 4 * j;
        const int u = t ^ (s2 << 2) ^ (f2 << 4);
        const float4 v = *reinterpret_cast<const float4*>(&q[s2 * CHUNK + u]);
        w[4 * j + 0] = v.x; w[4 * j + 1] = v.y;
        w[4 * j + 2] = v.z; w[4 * j + 3] = v.w;
      }
    }
  }

  // ---- pass 2: each lane sorts its (inst, frame) row of 64 ----
  sort_desc64(w);
  const float tau2 = sparsemax_tau(w);

  // ---- phase 3: broadcast row-taus; sources all from registers ----
#pragma unroll
  for (int i = 0; i < N_INST; ++i) {
    const int srclane = i * 4 + wf2;  // pass-2 lane holding tau for (i, wf2)
    const float taui = __int_as_float(
        __builtin_amdgcn_ds_bpermute(srclane << 2, __float_as_int(tau2)));
    float4 o;
    o.x = fmaxf(A[i][0] - taui, 0.0f);
    o.y = fmaxf(A[i][1] - taui, 0.0f);
    o.z = fmaxf(A[i][2] - taui, 0.0f);
    o.w = fmaxf(A[i][3] - taui, 0.0f);
    *reinterpret_cast<float4*>(out + base + (size_t)i * T_DIM) = o;
  }
}

extern "C" void kernel_launch(void* const* d_in, const int* in_sizes, int n_in,
                              void* d_out, int out_size, void* d_ws, size_t ws_size,
                              hipStream_t stream) {
  const float* in = (const float*)d_in[0];
  float* out = (float*)d_out;
  const int grid = B_DIM * NCHUNK / WPB;  // 2048 blocks x 4 waves
  seq_sparsemax_kernel<<<grid, 64 * WPB, 0, stream>>>(in, out);
}